// Round 1
// baseline (23.782 us; speedup 1.0000x reference)
//
#include <hip/hip_runtime.h>
#include <hip/hip_bf16.h>

// SocialPooling: out[i,g,h] = sum_j valid(i,j)&&cell(i,j)==g ? ht[j,h] : 0
// Key structural fact: same_scene_mask is SORTED -> scenes are contiguous
// blocks; only intra-block pairs can be valid. One block per row i, one wave
// (64 threads = HIDDEN), thread h owns hidden channel h.

#define GRID_G 4          // GRID_SIZE^2
#define HALF   0.8f       // AREA_SPAN/2
#define CELL   0.8f       // AREA_SPAN/GRID_SIZE
#define EPSV   0.01f

__global__ __launch_bounds__(64) void social_pool_kernel(
    const float* __restrict__ ht,      // (n, hidden)
    const float* __restrict__ pos,     // (n, 2)
    const int*   __restrict__ scene,   // (n,) sorted
    float*       __restrict__ out,     // (n, G, hidden)
    int n, int hidden)
{
    const int i = blockIdx.x;
    const int h = threadIdx.x;

    const int   s  = scene[i];
    const float px = pos[2 * i + 0];
    const float py = pos[2 * i + 1];

    // lower_bound(scene, s) — uniform across the wave
    int lo = 0, hi = n;
    while (lo < hi) {
        int mid = (lo + hi) >> 1;
        if (scene[mid] < s) lo = mid + 1; else hi = mid;
    }
    const int start = lo;
    // upper_bound(scene, s)
    hi = n;
    while (lo < hi) {
        int mid = (lo + hi) >> 1;
        if (scene[mid] <= s) lo = mid + 1; else hi = mid;
    }
    const int end = lo;

    float acc0 = 0.f, acc1 = 0.f, acc2 = 0.f, acc3 = 0.f;

    const float hi_b = HALF - EPSV;   // 0.79f
    const float lo_b = -HALF + EPSV;  // -0.79f

    for (int j = start; j < end; ++j) {
        if (j == i) continue;
        const float rx = pos[2 * j + 0] - px;
        const float ry = pos[2 * j + 1] - py;
        // strict interior of the window (wave-uniform predicate)
        if (!(rx < hi_b && rx > lo_b && ry < hi_b && ry > lo_b)) continue;
        const int gx = (int)floorf((rx + HALF) / CELL);
        const int gy = (int)floorf((ry + HALF) / CELL);
        const int g  = gx * 2 + gy;   // in {0,1,2,3} for valid pairs
        const float v = ht[(long)j * hidden + h];  // coalesced 256B per j
        // g is wave-uniform -> no divergence, just uniform branch
        if      (g == 0) acc0 += v;
        else if (g == 1) acc1 += v;
        else if (g == 2) acc2 += v;
        else             acc3 += v;
    }

    float* o = out + (long)i * GRID_G * hidden + h;
    o[0 * hidden] = acc0;
    o[1 * hidden] = acc1;
    o[2 * hidden] = acc2;
    o[3 * hidden] = acc3;
}

extern "C" void kernel_launch(void* const* d_in, const int* in_sizes, int n_in,
                              void* d_out, int out_size, void* d_ws, size_t ws_size,
                              hipStream_t stream)
{
    const float* ht    = (const float*)d_in[0];   // (n,1,hidden) f32
    const float* pos   = (const float*)d_in[1];   // (n,1,2) f32
    const int*   scene = (const int*)d_in[2];     // (n,1) int (sorted)
    float*       out   = (float*)d_out;           // (n, 4, hidden) f32

    const int n      = in_sizes[2];               // 4096
    const int hidden = in_sizes[0] / n;           // 64

    social_pool_kernel<<<n, hidden, 0, stream>>>(ht, pos, scene, out, n, hidden);
}